// Round 14
// baseline (15.289 us; speedup 1.0000x reference)
//
#include <hip/hip_runtime.h>
#include <math.h>

#define HH 512
#define WW 512
#define NG 1000
#define STEP (1.0f / 511.0f)
#define CHUNKS 4  // ceil(NG/256)

// Early-exit threshold: clip saturates at 1.0. Accumulation is monotone
// (every term e*c >= 0), so measured partial > THR => true sum > 1 => final
// clipped value == 1 exactly. 1.06/1.031 > 1 covers Schraudolph's +/-3%.
#define SAT_THR 1.06f

// Schraudolph exp2 bias: 127*2^23 - 366393 (centers rel err to ~+/-3%).
#define SCH_BIAS 1064986823.0f
// 2^11.5 — folded into rotation rows so a'^2 = a^2 * 2^23.
#define SCALE23 2896.309376f

__device__ __forceinline__ float clamp01(float v) {
    return fminf(fmaxf(v, 0.0f), 1.0f);
}

__device__ __forceinline__ float bits2e(float s) {
    return __uint_as_float((unsigned int)s);
}

// Single-block kernel: prep all params AND write them to d_ws permuted so
// high-contribution gaussians (key = min-channel color x sigma_x*sigma_y)
// come first. Render's per-wave early exit then fires after ~tens of
// gaussians instead of ~210 (random order). The clipped result is
// permutation-invariant (monotone terms; FP reassoc ~1e-6 << 2e-2 tol).
// Rank = stable 4-class partition via one Hillis-Steele scan over packed
// 16-bit-per-class counters -> fully deterministic (no atomics).
__global__ __launch_bounds__(256) void gs_order(
        const float* __restrict__ pos,
        const float* __restrict__ sc,
        const float* __restrict__ rot,
        const float* __restrict__ col,
        const float* __restrict__ op,
        float4* __restrict__ q0s,
        float4* __restrict__ q1s,
        float*  __restrict__ cbs) {
    __shared__ unsigned long long sA[NG], sB[NG];  // 16 KB
    const int tid = threadIdx.x;
    const float K = 0.84932180f;  // sqrt(0.5 * log2(e))

    float4 rp0[CHUNKS], rp1[CHUNKS];
    float  rcb[CHUNKS];
    int    rcl[CHUNKS];

#pragma unroll
    for (int j = 0; j < CHUNKS; ++j) {
        const int g = tid + j * 256;
        if (g < NG) {
            const float px = pos[2 * g + 0];
            const float py = pos[2 * g + 1];
            const float sx = fabsf(sc[2 * g + 0]) + 1e-6f;
            const float sy = fabsf(sc[2 * g + 1]) + 1e-6f;
            const float r  = rot[g];
            const float cth = __cosf(r);
            const float sth = __sinf(r);
            const float isx = SCALE23 * K / sx;
            const float isy = SCALE23 * K / sy;
            const float rxx = cth * isx;
            const float rxy = sth * isx;
            const float ryx = -sth * isy;
            const float ryy = cth * isy;
            const float ox = rxx * px + rxy * py;
            const float oy = ryx * px + ryy * py;
            const float so = 1.0f / (1.0f + __expf(-op[g]));
            const float cr = so / (1.0f + __expf(-col[3 * g + 0]));
            const float cg = so / (1.0f + __expf(-col[3 * g + 1]));
            const float cb = so / (1.0f + __expf(-col[3 * g + 2]));
            rp0[j] = make_float4(rxx, rxy, ryx, ryy);
            rp1[j] = make_float4(ox, oy, cr, cg);
            rcb[j] = cb;
            const float key = fminf(cr, fminf(cg, cb)) * sx * sy;
            const int cl = key > 0.15f ? 0 : key > 0.05f ? 1 : key > 0.01f ? 2 : 3;
            rcl[j] = cl;
            sA[g] = 1ull << (16 * cl);
        }
    }
    __syncthreads();

    // Hillis-Steele inclusive scan over packed per-class counters.
    unsigned long long* src = sA;
    unsigned long long* dst = sB;
    for (int off = 1; off < NG; off <<= 1) {
#pragma unroll
        for (int j = 0; j < CHUNKS; ++j) {
            const int i = tid + j * 256;
            if (i < NG) {
                unsigned long long v = src[i];
                if (i >= off) v += src[i - off];
                dst[i] = v;
            }
        }
        __syncthreads();
        unsigned long long* t = src; src = dst; dst = t;
    }

    const unsigned long long tot = src[NG - 1];
    const unsigned int t0 = (unsigned int)(tot & 0xFFFF);
    const unsigned int t1 = (unsigned int)((tot >> 16) & 0xFFFF);
    const unsigned int t2 = (unsigned int)((tot >> 32) & 0xFFFF);
    const unsigned int start[4] = {0u, t0, t0 + t1, t0 + t1 + t2};

#pragma unroll
    for (int j = 0; j < CHUNKS; ++j) {
        const int g = tid + j * 256;
        if (g < NG) {
            const int cl = rcl[j];
            const unsigned int cnt =
                (unsigned int)((src[g] >> (16 * cl)) & 0xFFFF);
            const int rank = (int)(start[cl] + cnt - 1u);
            q0s[rank] = rp0[j];
            q1s[rank] = rp1[j];
            cbs[rank] = rcb[j];
        }
    }
}

// One pixel/thread; params staged to LDS (36 KB -> 4 blocks/CU). Early exit
// per wave every 8 gaussians; with contribution-sorted order most waves exit
// within the first few chunks.
__global__ __launch_bounds__(256) void gs_render(
        const float4* __restrict__ q0s,
        const float4* __restrict__ q1s,
        const float*  __restrict__ cbs,
        float* __restrict__ out) {
    __shared__ float4 sQ0[NG];
    __shared__ float4 sQ1[NG];
    __shared__ float  sCb[NG];

    const int tid = threadIdx.x;
    for (int i = tid; i < NG; i += 256) {
        sQ0[i] = q0s[i];
        sQ1[i] = q1s[i];
        sCb[i] = cbs[i];
    }
    __syncthreads();

    const int idx = blockIdx.x * 256 + tid;
    const float y = (float)(idx >> 9) * STEP;
    const float x = (float)(idx & 511) * STEP;

    float aR = 0.f, aG = 0.f, aB = 0.f;

    for (int g = 0; g < NG; g += 8) {
#pragma unroll
        for (int k = 0; k < 8; ++k) {
            const float4 q0 = sQ0[g + k];
            const float4 q1 = sQ1[g + k];
            const float  cb = sCb[g + k];
            const float a = fmaf(q0.x, x, fmaf(q0.y, y, -q1.x));
            const float b = fmaf(q0.z, x, fmaf(q0.w, y, -q1.y));
            const float e = bits2e(fmaf(-a, a, fmaf(-b, b, SCH_BIAS)));
            aR = fmaf(e, q1.z, aR);
            aG = fmaf(e, q1.w, aG);
            aB = fmaf(e, cb, aB);
        }
        if (__all(fminf(fminf(aR, aG), aB) > SAT_THR)) {
            break;
        }
    }

    const int hw = HH * WW;
    out[0 * hw + idx] = clamp01(aR);
    out[1 * hw + idx] = clamp01(aG);
    out[2 * hw + idx] = clamp01(aB);
}

extern "C" void kernel_launch(void* const* d_in, const int* in_sizes, int n_in,
                              void* d_out, int out_size, void* d_ws, size_t ws_size,
                              hipStream_t stream) {
    const float* pos = (const float*)d_in[0];  // [1000,2]
    const float* sc  = (const float*)d_in[1];  // [1000,2]
    const float* rot = (const float*)d_in[2];  // [1000]
    const float* col = (const float*)d_in[3];  // [1000,3]
    const float* op  = (const float*)d_in[4];  // [1000]
    float* out = (float*)d_out;                // [3,512,512]

    float4* q0s = (float4*)d_ws;                            // 16 KB
    float4* q1s = (float4*)((char*)d_ws + 16384);           // 16 KB
    float*  cbs = (float*)((char*)d_ws + 32768);            // 4 KB

    gs_order<<<1, 256, 0, stream>>>(pos, sc, rot, col, op, q0s, q1s, cbs);
    gs_render<<<(HH * WW) / 256, 256, 0, stream>>>(q0s, q1s, cbs, out);
}

// Round 15
// 12.957 us; speedup vs baseline: 1.1800x; 1.1800x over previous
//
#include <hip/hip_runtime.h>
#include <math.h>

#define HH 512
#define WW 512
#define NG 1000
#define STEP (1.0f / 511.0f)
#define CHUNKS 4  // ceil(NG/256)

// Early-exit threshold: clip saturates at 1.0. Accumulation is monotone
// (every term e*c >= 0), so measured partial > THR => true sum > 1 => final
// clipped value == 1 exactly. 1.06/1.031 > 1 covers Schraudolph's +/-3%.
#define SAT_THR 1.06f

// Schraudolph exp2 bias: 127*2^23 - 366393 (centers rel err to ~+/-3%).
#define SCH_BIAS 1064986823.0f
// 2^11.5 — folded into rotation rows so a'^2 = a^2 * 2^23.
#define SCALE23 2896.309376f

__device__ __forceinline__ float clamp01(float v) {
    return fminf(fmaxf(v, 0.0f), 1.0f);
}

__device__ __forceinline__ float bits2e(float s) {
    // cvt_u32 saturates negatives to 0 -> exact 0 for far pixels.
    return __uint_as_float((unsigned int)s);
}

// Single fused kernel (one launch -- r13/r14 showed each extra launch costs
// ~3.8 us here).
// Phase 1: each block preps all 1000 gaussians' params AND scatters them
// into LDS in contribution-class-major order (key = min-channel color x
// sigma_x*sigma_y; 4 classes). Rank is deterministic: per-wave per-class
// __ballot lane-prefix + a 64-counter serial exclusive scan on thread 0.
// The clipped result is permutation-invariant (monotone terms, FP reassoc
// ~1e-6 << 2e-2), so reordering only changes SPEED of saturation.
// Phase 2: one pixel/thread; per-wave early exit every 8 gaussians. With
// big/bright gaussians first, waves exit after ~tens instead of ~210.
__global__ __launch_bounds__(256) void gs_fused(
        const float* __restrict__ pos,
        const float* __restrict__ sc,
        const float* __restrict__ rot,
        const float* __restrict__ col,
        const float* __restrict__ op,
        float* __restrict__ out) {
    __shared__ float4 sQ0[NG];                // 16 KB
    __shared__ float4 sQ1[NG];                // 16 KB
    __shared__ float  sCb[NG];                // 4 KB
    __shared__ int    wcnt[CHUNKS][4][4];     // [chunk][wave][class]
    __shared__ int    woff[CHUNKS][4][4];

    const int tid  = threadIdx.x;
    const int lane = tid & 63;
    const int wav  = tid >> 6;
    const unsigned long long ltmask = (1ull << lane) - 1ull;
    const float K = 0.84932180f;  // sqrt(0.5 * log2(e))

    float4 rp0[CHUNKS], rp1[CHUNKS];
    float  rcb[CHUNKS];
    int    rcl[CHUNKS], rpre[CHUNKS];

#pragma unroll
    for (int j = 0; j < CHUNKS; ++j) {
        const int g = tid + j * 256;
        const bool valid = g < NG;
        int cl = 3;
        if (valid) {
            const float px = pos[2 * g + 0];
            const float py = pos[2 * g + 1];
            const float sx = fabsf(sc[2 * g + 0]) + 1e-6f;
            const float sy = fabsf(sc[2 * g + 1]) + 1e-6f;
            const float r  = rot[g];
            const float cth = __cosf(r);
            const float sth = __sinf(r);
            const float isx = SCALE23 * K / sx;
            const float isy = SCALE23 * K / sy;
            const float rxx = cth * isx;
            const float rxy = sth * isx;
            const float ryx = -sth * isy;
            const float ryy = cth * isy;
            const float ox = rxx * px + rxy * py;
            const float oy = ryx * px + ryy * py;
            const float so = 1.0f / (1.0f + __expf(-op[g]));
            const float cr = so / (1.0f + __expf(-col[3 * g + 0]));
            const float cg = so / (1.0f + __expf(-col[3 * g + 1]));
            const float cb = so / (1.0f + __expf(-col[3 * g + 2]));
            rp0[j] = make_float4(rxx, rxy, ryx, ryy);
            rp1[j] = make_float4(ox, oy, cr, cg);
            rcb[j] = cb;
            const float key = fminf(cr, fminf(cg, cb)) * sx * sy;
            cl = key > 0.15f ? 0 : key > 0.05f ? 1 : key > 0.01f ? 2 : 3;
        }
        rcl[j] = cl;
        const unsigned long long m0 = __ballot(valid && cl == 0);
        const unsigned long long m1 = __ballot(valid && cl == 1);
        const unsigned long long m2 = __ballot(valid && cl == 2);
        const unsigned long long m3 = __ballot(valid && cl == 3);
        if (lane == 0) {
            wcnt[j][wav][0] = __popcll(m0);
            wcnt[j][wav][1] = __popcll(m1);
            wcnt[j][wav][2] = __popcll(m2);
            wcnt[j][wav][3] = __popcll(m3);
        }
        const unsigned long long mym =
            cl == 0 ? m0 : cl == 1 ? m1 : cl == 2 ? m2 : m3;
        rpre[j] = (int)__popcll(mym & ltmask);
    }
    __syncthreads();

    if (tid == 0) {
        int run = 0;
        for (int c = 0; c < 4; ++c)
            for (int j = 0; j < CHUNKS; ++j)
                for (int w = 0; w < 4; ++w) {
                    woff[j][w][c] = run;
                    run += wcnt[j][w][c];
                }
    }
    __syncthreads();

#pragma unroll
    for (int j = 0; j < CHUNKS; ++j) {
        const int g = tid + j * 256;
        if (g < NG) {
            const int rank = woff[j][wav][rcl[j]] + rpre[j];
            sQ0[rank] = rp0[j];
            sQ1[rank] = rp1[j];
            sCb[rank] = rcb[j];
        }
    }
    __syncthreads();

    const int idx = blockIdx.x * 256 + tid;
    const float y = (float)(idx >> 9) * STEP;
    const float x = (float)(idx & 511) * STEP;

    float aR = 0.f, aG = 0.f, aB = 0.f;

    // 1000 = 8 * 125: exact chunking, no tail loop.
    for (int g = 0; g < NG; g += 8) {
#pragma unroll
        for (int k = 0; k < 8; ++k) {
            const float4 q0 = sQ0[g + k];
            const float4 q1 = sQ1[g + k];
            const float  cb = sCb[g + k];
            const float a = fmaf(q0.x, x, fmaf(q0.y, y, -q1.x));
            const float b = fmaf(q0.z, x, fmaf(q0.w, y, -q1.y));
            const float e = bits2e(fmaf(-a, a, fmaf(-b, b, SCH_BIAS)));
            aR = fmaf(e, q1.z, aR);
            aG = fmaf(e, q1.w, aG);
            aB = fmaf(e, cb, aB);
        }
        if (__all(fminf(fminf(aR, aG), aB) > SAT_THR)) {
            break;
        }
    }

    const int hw = HH * WW;
    out[0 * hw + idx] = clamp01(aR);
    out[1 * hw + idx] = clamp01(aG);
    out[2 * hw + idx] = clamp01(aB);
}

extern "C" void kernel_launch(void* const* d_in, const int* in_sizes, int n_in,
                              void* d_out, int out_size, void* d_ws, size_t ws_size,
                              hipStream_t stream) {
    const float* pos = (const float*)d_in[0];  // [1000,2]
    const float* sc  = (const float*)d_in[1];  // [1000,2]
    const float* rot = (const float*)d_in[2];  // [1000]
    const float* col = (const float*)d_in[3];  // [1000,3]
    const float* op  = (const float*)d_in[4];  // [1000]
    float* out = (float*)d_out;                // [3,512,512]

    gs_fused<<<(HH * WW) / 256, 256, 0, stream>>>(pos, sc, rot, col, op, out);
}

// Round 16
// 11.166 us; speedup vs baseline: 1.3693x; 1.1604x over previous
//
#include <hip/hip_runtime.h>
#include <math.h>

#define HH 512
#define WW 512
#define NG 1000
#define STEP (1.0f / 511.0f)

// Early-exit threshold: clip saturates at 1.0. Accumulation is monotone
// (every term e*c >= 0), so measured partial > THR => true sum > 1 => final
// clipped value == 1 exactly. 1.06/1.031 > 1 covers Schraudolph's +/-3%.
#define SAT_THR 1.06f

// Schraudolph exp2 bias: 127*2^23 - 366393 (centers rel err to ~+/-3%).
#define SCH_BIAS 1064986823.0f
// 2^11.5 — folded into rotation rows so a'^2 = a^2 * 2^23.
#define SCALE23 2896.309376f

__device__ __forceinline__ float clamp01(float v) {
    return fminf(fmaxf(v, 0.0f), 1.0f);
}

__device__ __forceinline__ float bits2e(float s) {
    // cvt_u32 saturates negatives to 0 -> exact 0 for far pixels.
    return __uint_as_float((unsigned int)s);
}

// Single fused kernel, one block = HALF A ROW (256 px, P=1/thread).
// Because y is block-uniform, the per-gaussian row constants
//   A = rxy'*y - ox', B = ryy'*y - oy'
// are hoisted into the prep phase (computed once per block instead of per
// pixel*gaussian): the hot loop is 8 VALU + 2 LDS broadcasts per gaussian
// (r13 was 12 + 3). Math is op-identical to r13 -> bitwise same output.
// LDS 32 KB -> 4 blocks/CU, 4 waves/SIMD (same occupancy as r13).
__global__ __launch_bounds__(256) void gs_fused(
        const float* __restrict__ pos,
        const float* __restrict__ sc,
        const float* __restrict__ rot,
        const float* __restrict__ col,
        const float* __restrict__ op,
        float* __restrict__ out) {
    __shared__ float4 sP[NG];  // rxx', ryx', A, B   (16 KB)
    __shared__ float4 sC[NG];  // cr, cg, cb, 0      (16 KB)

    const int tid = threadIdx.x;
    const int row  = blockIdx.x >> 1;
    const int colb = (blockIdx.x & 1) << 8;  // 0 or 256
    const float y = (float)row * STEP;
    const float K = 0.84932180f;  // sqrt(0.5 * log2(e))

    for (int g = tid; g < NG; g += 256) {
        const float px = pos[2 * g + 0];
        const float py = pos[2 * g + 1];
        const float sx = fabsf(sc[2 * g + 0]) + 1e-6f;
        const float sy = fabsf(sc[2 * g + 1]) + 1e-6f;
        const float r  = rot[g];
        const float cth = __cosf(r);
        const float sth = __sinf(r);
        const float isx = SCALE23 * K / sx;
        const float isy = SCALE23 * K / sy;
        const float rxx = cth * isx;
        const float rxy = sth * isx;
        const float ryx = -sth * isy;
        const float ryy = cth * isy;
        const float ox = rxx * px + rxy * py;
        const float oy = ryx * px + ryy * py;
        // Row constants for this block's y (op-identical to the in-loop
        // fmaf(rxy, y, -ox) of r13).
        const float A = fmaf(rxy, y, -ox);
        const float B = fmaf(ryy, y, -oy);
        const float so = 1.0f / (1.0f + __expf(-op[g]));
        const float cr = so / (1.0f + __expf(-col[3 * g + 0]));
        const float cg = so / (1.0f + __expf(-col[3 * g + 1]));
        const float cb = so / (1.0f + __expf(-col[3 * g + 2]));
        sP[g] = make_float4(rxx, ryx, A, B);
        sC[g] = make_float4(cr, cg, cb, 0.0f);
    }
    __syncthreads();

    const float x = (float)(colb + tid) * STEP;

    float aR = 0.f, aG = 0.f, aB = 0.f;

    // 1000 = 8 * 125: exact chunking, no tail loop.
    for (int g = 0; g < NG; g += 8) {
#pragma unroll
        for (int k = 0; k < 8; ++k) {
            const float4 q0 = sP[g + k];
            const float4 q1 = sC[g + k];
            const float a = fmaf(q0.x, x, q0.z);
            const float b = fmaf(q0.y, x, q0.w);
            const float e = bits2e(fmaf(-a, a, fmaf(-b, b, SCH_BIAS)));
            aR = fmaf(e, q1.x, aR);
            aG = fmaf(e, q1.y, aG);
            aB = fmaf(e, q1.z, aB);
        }
        if (__all(fminf(fminf(aR, aG), aB) > SAT_THR)) {
            break;
        }
    }

    const int idx = row * WW + colb + tid;
    const int hw = HH * WW;
    out[0 * hw + idx] = clamp01(aR);
    out[1 * hw + idx] = clamp01(aG);
    out[2 * hw + idx] = clamp01(aB);
}

extern "C" void kernel_launch(void* const* d_in, const int* in_sizes, int n_in,
                              void* d_out, int out_size, void* d_ws, size_t ws_size,
                              hipStream_t stream) {
    const float* pos = (const float*)d_in[0];  // [1000,2]
    const float* sc  = (const float*)d_in[1];  // [1000,2]
    const float* rot = (const float*)d_in[2];  // [1000]
    const float* col = (const float*)d_in[3];  // [1000,3]
    const float* op  = (const float*)d_in[4];  // [1000]
    float* out = (float*)d_out;                // [3,512,512]

    gs_fused<<<HH * 2, 256, 0, stream>>>(pos, sc, rot, col, op, out);
}